// Round 2
// baseline (510.608 us; speedup 1.0000x reference)
//
#include <hip/hip_runtime.h>
#include <hip/hip_bf16.h>

typedef __bf16 bf16;
typedef __attribute__((ext_vector_type(8))) __bf16 bf16x8;
typedef __attribute__((ext_vector_type(4))) float f32x4;

#define DEV __device__ __forceinline__

// async global->LDS, 16B per lane; LDS dest = wave-uniform base + lane*16
DEV void gload_lds16(const void* g, void* l) {
  __builtin_amdgcn_global_load_lds(
      (__attribute__((address_space(1))) void*)(g),
      (__attribute__((address_space(3))) void*)(l), 16, 0, 0);
}

// ---------------- conversion kernels ----------------
// fp32 -> bf16, 8 elems/thread
__global__ void k_cvt_bf16(const float* __restrict__ in, bf16* __restrict__ out, int n8) {
  int i = blockIdx.x * blockDim.x + threadIdx.x;
  if (i >= n8) return;
  const float4* p = reinterpret_cast<const float4*>(in) + (size_t)i * 2;
  float4 a = p[0], b = p[1];
  bf16x8 o;
  o[0] = (bf16)a.x; o[1] = (bf16)a.y; o[2] = (bf16)a.z; o[3] = (bf16)a.w;
  o[4] = (bf16)b.x; o[5] = (bf16)b.y; o[6] = (bf16)b.z; o[7] = (bf16)b.w;
  *reinterpret_cast<bf16x8*>(out + (size_t)i * 8) = o;
}

// Wt[n][d] = W[h=n>>6][d][e=n&63]   (W: [16,1024,64] -> Wt: [1024,1024], bf16)
__global__ void k_cvt_wqkv(const float* __restrict__ W, bf16* __restrict__ Wt) {
  int idx = blockIdx.x * blockDim.x + threadIdx.x;  // covers 1<<20
  int d = idx & 1023, n = idx >> 10;
  Wt[idx] = (bf16)W[((size_t)(n >> 6) << 16) + (size_t)d * 64 + (n & 63)];
}

// WoT[n][k] = Wo[k][n]   (1024x1024 transpose, bf16)
__global__ void k_cvt_wo(const float* __restrict__ W, bf16* __restrict__ Wt) {
  int idx = blockIdx.x * blockDim.x + threadIdx.x;
  int k = idx & 1023, n = idx >> 10;
  Wt[idx] = (bf16)W[(size_t)k * 1024 + n];
}

// ---------------- GEMM: C = A[8192x1024] * Bt[1024x1024]^T ----------------
// m97-style: 128x128 tile, BK=32, 4 waves (2x2), 4x4 16x16x32 frags per wave.
// SMODE 0: bf16 out, scatter to [B,H,S,64]   (Q,K heads)
// SMODE 1: bf16 out, scatter to [B,H,64,S]   (V transposed; 4-row packed stores)
// SMODE 2: f32 out, plain [M][N]             (final projection -> d_out)
template <int SMODE>
__global__ __launch_bounds__(256) void k_gemm(const bf16* __restrict__ A,
                                              const bf16* __restrict__ Bt,
                                              void* __restrict__ Cout) {
  constexpr int K = 1024;
  __shared__ __align__(16) bf16 As[128 * 32];
  __shared__ __align__(16) bf16 Bs[128 * 32];
  const int tid = threadIdx.x;
  const int lane = tid & 63, w = tid >> 6;
  const int wr = w >> 1, wc = w & 1;
  const int lgrp = lane >> 4, lid = lane & 15;
  const int m0 = blockIdx.x * 128, n0 = blockIdx.y * 128;

  f32x4 acc[4][4] = {};

  // staging: 8KB tile = 8 chunks of 1KB; wave w owns chunks w*2, w*2+1
  const int c0 = w * 2, c1 = w * 2 + 1;
  const int bo0 = c0 * 1024 + lane * 16, bo1 = c1 * 1024 + lane * 16;
  const int r0 = bo0 >> 6, e0 = (bo0 & 63) >> 1;  // row, elem-in-row
  const int r1 = bo1 >> 6, e1 = (bo1 & 63) >> 1;

  for (int k0 = 0; k0 < K; k0 += 32) {
    __syncthreads();  // WAR: previous iter's frag reads done
    gload_lds16(A + (size_t)(m0 + r0) * K + k0 + e0, (char*)As + c0 * 1024);
    gload_lds16(A + (size_t)(m0 + r1) * K + k0 + e1, (char*)As + c1 * 1024);
    gload_lds16(Bt + (size_t)(n0 + r0) * K + k0 + e0, (char*)Bs + c0 * 1024);
    gload_lds16(Bt + (size_t)(n0 + r1) * K + k0 + e1, (char*)Bs + c1 * 1024);
    __syncthreads();  // compiler drains vmcnt(0) before s_barrier
    bf16x8 af[4], bfv[4];
    for (int m = 0; m < 4; ++m)
      af[m] = *reinterpret_cast<const bf16x8*>(&As[(wr * 64 + m * 16 + lid) * 32 + lgrp * 8]);
    for (int n = 0; n < 4; ++n)
      bfv[n] = *reinterpret_cast<const bf16x8*>(&Bs[(wc * 64 + n * 16 + lid) * 32 + lgrp * 8]);
    for (int m = 0; m < 4; ++m)
      for (int n = 0; n < 4; ++n)
        acc[m][n] = __builtin_amdgcn_mfma_f32_16x16x32_bf16(af[m], bfv[n], acc[m][n], 0, 0, 0);
  }

  // C layout per frag: row = (lane>>4)*4 + r, col = lane&15
  if constexpr (SMODE == 2) {
    float* C = (float*)Cout;
    for (int m = 0; m < 4; ++m) {
      int rowb = m0 + wr * 64 + m * 16 + lgrp * 4;
      for (int n = 0; n < 4; ++n) {
        int col = n0 + wc * 64 + n * 16 + lid;
        for (int r = 0; r < 4; ++r)
          C[(size_t)(rowb + r) * 1024 + col] = acc[m][n][r];
      }
    }
  } else if constexpr (SMODE == 0) {
    bf16* C = (bf16*)Cout;
    for (int m = 0; m < 4; ++m) {
      int rowb = m0 + wr * 64 + m * 16 + lgrp * 4;
      for (int n = 0; n < 4; ++n) {
        int col = n0 + wc * 64 + n * 16 + lid;
        int h = col >> 6, e = col & 63;
        for (int r = 0; r < 4; ++r) {
          int row = rowb + r;
          int b = row >> 11, s = row & 2047;
          C[(((size_t)b * 16 + h) * 2048 + s) * 64 + e] = (bf16)acc[m][n][r];
        }
      }
    }
  } else {  // SMODE 1: V^T [B,H,64,S]; 4 consecutive s per lane -> 8B packed store
    bf16* C = (bf16*)Cout;
    for (int m = 0; m < 4; ++m) {
      int rowb = m0 + wr * 64 + m * 16 + lgrp * 4;
      int b = rowb >> 11, s = rowb & 2047;  // 4-row group never crosses batch
      for (int n = 0; n < 4; ++n) {
        int col = n0 + wc * 64 + n * 16 + lid;
        int h = col >> 6, e = col & 63;
        union { bf16 hv[4]; uint2 u; } tmp;
        for (int r = 0; r < 4; ++r) tmp.hv[r] = (bf16)acc[m][n][r];
        bf16* dst = C + (((size_t)b * 16 + h) * 64 + e) * 2048 + s;
        *reinterpret_cast<uint2*>(dst) = tmp.u;
      }
    }
  }
}

// ---------------- flash attention ----------------
// Qh,Kh: [B,H,S,64] bf16; Vt: [B,H,64,S] bf16; Ob: [B,S,H*64] bf16
// block = 4 independent waves, each owns 16 q-rows; KV tile = 64 keys.
// blk->(b,h,qt) interleaves batches (b = blk&3) so every CU gets an equal
// per-batch work mix (work is proportional to valid_lens[b]).
__global__ __launch_bounds__(256) void k_flash(const bf16* __restrict__ Qh,
                                               const bf16* __restrict__ Kh,
                                               const bf16* __restrict__ Vt,
                                               const int* __restrict__ valid,
                                               bf16* __restrict__ Ob) {
  // per-wave 16x64 bf16 P buffer, XOR-swizzled rows (stride 128B)
  __shared__ __align__(16) char Plds[4][16 * 128];
  const int tid = threadIdx.x, lane = tid & 63, w = tid >> 6;
  const int lgrp = lane >> 4, lid = lane & 15;
  const int blk = blockIdx.x;
  const int b = blk & 3;
  const int rest = blk >> 2;
  const int h = rest & 15;
  const int qt = rest >> 4;  // 0..31
  const int bh = b * 16 + h;
  const int s0 = qt * 64 + w * 16;
  const bf16* Qp = Qh + ((size_t)bh * 2048 + s0) * 64;
  const bf16* Kp = Kh + (size_t)bh * 2048 * 64;
  const bf16* Vp = Vt + (size_t)bh * 64 * 2048;
  const int vl = valid[b];
  const int nt = (vl + 63) >> 6;  // skip fully-masked KV tiles

  // Q A-frags (row=lid, k=lgrp*8+j), K-dim 64 = 2 chunks
  bf16x8 aq0 = *reinterpret_cast<const bf16x8*>(Qp + lid * 64 + lgrp * 8);
  bf16x8 aq1 = *reinterpret_cast<const bf16x8*>(Qp + lid * 64 + 32 + lgrp * 8);

  f32x4 Of[4] = {};
  float mrow[4] = {-1e30f, -1e30f, -1e30f, -1e30f};
  float lrow[4] = {0.f, 0.f, 0.f, 0.f};
  char* Pw = &Plds[w][0];

  for (int t = 0; t < nt; ++t) {
    const int t0 = t * 64;
    // scores S[16q][64k] = Q * K^T, four 16-col frags
    f32x4 sc[4] = {};
#pragma unroll
    for (int ct = 0; ct < 4; ++ct) {
      const bf16* kp = Kp + (size_t)(t0 + ct * 16 + lid) * 64 + lgrp * 8;
      bf16x8 bk0 = *reinterpret_cast<const bf16x8*>(kp);
      bf16x8 bk1 = *reinterpret_cast<const bf16x8*>(kp + 32);
      sc[ct] = __builtin_amdgcn_mfma_f32_16x16x32_bf16(aq0, bk0, sc[ct], 0, 0, 0);
      sc[ct] = __builtin_amdgcn_mfma_f32_16x16x32_bf16(aq1, bk1, sc[ct], 0, 0, 0);
    }
    // scale 1/sqrt(64) + padding mask (col >= vl)
#pragma unroll
    for (int ct = 0; ct < 4; ++ct) {
      const bool masked = (t0 + ct * 16 + lid) >= vl;
#pragma unroll
      for (int r = 0; r < 4; ++r)
        sc[ct][r] = masked ? -1e30f : sc[ct][r] * 0.125f;
    }
    // online softmax: row = lgrp*4 + r, 16 cols spread over 16-lane group
    float scale[4];
#pragma unroll
    for (int r = 0; r < 4; ++r) {
      float vm = fmaxf(fmaxf(sc[0][r], sc[1][r]), fmaxf(sc[2][r], sc[3][r]));
      vm = fmaxf(vm, __shfl_xor(vm, 1));
      vm = fmaxf(vm, __shfl_xor(vm, 2));
      vm = fmaxf(vm, __shfl_xor(vm, 4));
      vm = fmaxf(vm, __shfl_xor(vm, 8));
      float mnew = fmaxf(mrow[r], vm);
      scale[r] = __expf(mrow[r] - mnew);
      mrow[r] = mnew;
    }
#pragma unroll
    for (int ct = 0; ct < 4; ++ct)
#pragma unroll
      for (int r = 0; r < 4; ++r)
        sc[ct][r] = __expf(sc[ct][r] - mrow[r]);  // masked -> exp(-huge)=0
#pragma unroll
    for (int r = 0; r < 4; ++r) {
      float s = (sc[0][r] + sc[1][r]) + (sc[2][r] + sc[3][r]);
      s += __shfl_xor(s, 1);
      s += __shfl_xor(s, 2);
      s += __shfl_xor(s, 4);
      s += __shfl_xor(s, 8);
      lrow[r] = lrow[r] * scale[r] + s;
    }
    // P: C-layout -> LDS (swizzled) -> A-layout (within-wave, no barrier)
#pragma unroll
    for (int ct = 0; ct < 4; ++ct)
#pragma unroll
      for (int r = 0; r < 4; ++r) {
        const int row = lgrp * 4 + r;
        const int cb = (ct * 16 + lid) * 2;
        *reinterpret_cast<bf16*>(Pw + row * 128 + (cb ^ ((row & 7) << 4))) = (bf16)sc[ct][r];
      }
    asm volatile("s_waitcnt lgkmcnt(0)" ::: "memory");
    bf16x8 pa0 = *reinterpret_cast<const bf16x8*>(Pw + lid * 128 + ((lgrp * 16) ^ ((lid & 7) << 4)));
    bf16x8 pa1 = *reinterpret_cast<const bf16x8*>(Pw + lid * 128 + ((64 + lgrp * 16) ^ ((lid & 7) << 4)));
    // rescale O accumulator, then PV (B-operand contiguous thanks to V^T layout)
#pragma unroll
    for (int f = 0; f < 4; ++f)
#pragma unroll
      for (int r = 0; r < 4; ++r)
        Of[f][r] *= scale[r];
#pragma unroll
    for (int f = 0; f < 4; ++f) {
      const bf16* vp = Vp + (size_t)(f * 16 + lid) * 2048 + t0 + lgrp * 8;
      bf16x8 bv0 = *reinterpret_cast<const bf16x8*>(vp);
      bf16x8 bv1 = *reinterpret_cast<const bf16x8*>(vp + 32);
      Of[f] = __builtin_amdgcn_mfma_f32_16x16x32_bf16(pa0, bv0, Of[f], 0, 0, 0);
      Of[f] = __builtin_amdgcn_mfma_f32_16x16x32_bf16(pa1, bv1, Of[f], 0, 0, 0);
    }
  }
  // epilogue: O/l, store bf16 to [B,S,H*64]
  bf16* Op = Ob + ((size_t)b * 2048 + s0) * 1024 + h * 64;
#pragma unroll
  for (int r = 0; r < 4; ++r) {
    float inv = 1.f / lrow[r];
#pragma unroll
    for (int f = 0; f < 4; ++f)
      Op[(size_t)(lgrp * 4 + r) * 1024 + f * 16 + lid] = (bf16)(Of[f][r] * inv);
  }
}

// ---------------- launch ----------------
extern "C" void kernel_launch(void* const* d_in, const int* in_sizes, int n_in,
                              void* d_out, int out_size, void* d_ws, size_t ws_size,
                              hipStream_t stream) {
  const float* q = (const float*)d_in[0];
  const float* k = (const float*)d_in[1];
  const float* v = (const float*)d_in[2];
  const int* vl = (const int*)d_in[3];
  const float* Wq = (const float*)d_in[4];
  const float* Wk = (const float*)d_in[5];
  const float* Wv = (const float*)d_in[6];
  const float* Wo = (const float*)d_in[7];

  char* ws = (char*)d_ws;
  const size_t SZW = (size_t)1024 * 1024 * 2;  // 2MB  (transposed bf16 weight)
  const size_t SZT = (size_t)8192 * 1024 * 2;  // 16MB (bf16 activation tensor)
  bf16* WqT = (bf16*)(ws);
  bf16* WkT = (bf16*)(ws + SZW);
  bf16* WvT = (bf16*)(ws + 2 * SZW);
  bf16* WoT = (bf16*)(ws + 3 * SZW);
  bf16* Qh  = (bf16*)(ws + 4 * SZW);
  bf16* Kh  = (bf16*)(ws + 4 * SZW + SZT);
  bf16* Vt  = (bf16*)(ws + 4 * SZW + 2 * SZT);
  bf16* qb  = (bf16*)(ws + 4 * SZW + 3 * SZT);
  bf16* kb  = (bf16*)(ws + 4 * SZW + 4 * SZT);
  bf16* vb  = (bf16*)(ws + 4 * SZW + 5 * SZT);
  bf16* attnb = qb;  // qb dead after Q projection; reuse for attention output

  k_cvt_bf16<<<4096, 256, 0, stream>>>(q, qb, 1 << 20);
  k_cvt_bf16<<<4096, 256, 0, stream>>>(k, kb, 1 << 20);
  k_cvt_bf16<<<4096, 256, 0, stream>>>(v, vb, 1 << 20);
  k_cvt_wqkv<<<4096, 256, 0, stream>>>(Wq, WqT);
  k_cvt_wqkv<<<4096, 256, 0, stream>>>(Wk, WkT);
  k_cvt_wqkv<<<4096, 256, 0, stream>>>(Wv, WvT);
  k_cvt_wo<<<4096, 256, 0, stream>>>(Wo, WoT);

  dim3 gg(64, 8);  // M/128 x N/128
  k_gemm<0><<<gg, 256, 0, stream>>>(qb, WqT, Qh);
  k_gemm<0><<<gg, 256, 0, stream>>>(kb, WkT, Kh);
  k_gemm<1><<<gg, 256, 0, stream>>>(vb, WvT, Vt);
  k_flash<<<2048, 256, 0, stream>>>(Qh, Kh, Vt, vl, attnb);
  k_gemm<2><<<gg, 256, 0, stream>>>(attnb, WoT, d_out);
}

// Round 3
// 277.034 us; speedup vs baseline: 1.8431x; 1.8431x over previous
//
#include <hip/hip_runtime.h>
#include <hip/hip_bf16.h>

typedef __bf16 bf16;
typedef __attribute__((ext_vector_type(8))) __bf16 bf16x8;
typedef __attribute__((ext_vector_type(4))) float f32x4;

#define DEV __device__ __forceinline__

// async global->LDS, 16B per lane; LDS dest = wave-uniform base + lane*16
DEV void gload_lds16(const void* g, void* l) {
  __builtin_amdgcn_global_load_lds(
      (__attribute__((address_space(1))) void*)(g),
      (__attribute__((address_space(3))) void*)(l), 16, 0, 0);
}

// ---------------- conversion kernels ----------------
__global__ void k_cvt_bf16(const float* __restrict__ in, bf16* __restrict__ out, int n8) {
  int i = blockIdx.x * blockDim.x + threadIdx.x;
  if (i >= n8) return;
  const float4* p = reinterpret_cast<const float4*>(in) + (size_t)i * 2;
  float4 a = p[0], b = p[1];
  bf16x8 o;
  o[0] = (bf16)a.x; o[1] = (bf16)a.y; o[2] = (bf16)a.z; o[3] = (bf16)a.w;
  o[4] = (bf16)b.x; o[5] = (bf16)b.y; o[6] = (bf16)b.z; o[7] = (bf16)b.w;
  *reinterpret_cast<bf16x8*>(out + (size_t)i * 8) = o;
}

// Wt[n][d] = W[h=n>>6][d][e=n&63]   (W: [16,1024,64] -> Wt: [1024,1024], bf16)
__global__ void k_cvt_wqkv(const float* __restrict__ W, bf16* __restrict__ Wt) {
  int idx = blockIdx.x * blockDim.x + threadIdx.x;  // covers 1<<20
  int d = idx & 1023, n = idx >> 10;
  Wt[idx] = (bf16)W[((size_t)(n >> 6) << 16) + (size_t)d * 64 + (n & 63)];
}

// WoT[n][k] = Wo[k][n]   (1024x1024 transpose, bf16)
__global__ void k_cvt_wo(const float* __restrict__ W, bf16* __restrict__ Wt) {
  int idx = blockIdx.x * blockDim.x + threadIdx.x;
  int k = idx & 1023, n = idx >> 10;
  Wt[idx] = (bf16)W[(size_t)k * 1024 + n];
}

// ---------------- GEMM: C = A[8192x1024] * Bt[1024x1024]^T ----------------
// SMODE 0: bf16 out, scatter to [B,H,S,64]                    (Q heads, plain)
// SMODE 3: bf16 out, scatter to [B,H,S,64], XOR-swizzled rows (K heads)
// SMODE 1: bf16 out, scatter to [B,H,64,S], XOR-swizzled rows (V transposed)
// SMODE 2: f32 out, plain [M][N]                              (final proj)
// Swizzle: within each 128B (64-elem) row r, element e stored at e^((r&7)<<3)
// so the flash kernel can stage LINEARLY with global_load_lds and read with
// the same XOR -> conflict-free ds_read_b128 (rule #21 both-sides pattern).
template <int SMODE>
__global__ __launch_bounds__(256) void k_gemm(const bf16* __restrict__ A,
                                              const bf16* __restrict__ Bt,
                                              void* __restrict__ Cout) {
  constexpr int K = 1024;
  __shared__ __align__(16) bf16 As[128 * 32];
  __shared__ __align__(16) bf16 Bs[128 * 32];
  const int tid = threadIdx.x;
  const int lane = tid & 63, w = tid >> 6;
  const int wr = w >> 1, wc = w & 1;
  const int lgrp = lane >> 4, lid = lane & 15;
  const int m0 = blockIdx.x * 128, n0 = blockIdx.y * 128;

  f32x4 acc[4][4] = {};

  const int c0 = w * 2, c1 = w * 2 + 1;
  const int bo0 = c0 * 1024 + lane * 16, bo1 = c1 * 1024 + lane * 16;
  const int r0 = bo0 >> 6, e0 = (bo0 & 63) >> 1;
  const int r1 = bo1 >> 6, e1 = (bo1 & 63) >> 1;

  for (int k0 = 0; k0 < K; k0 += 32) {
    __syncthreads();
    gload_lds16(A + (size_t)(m0 + r0) * K + k0 + e0, (char*)As + c0 * 1024);
    gload_lds16(A + (size_t)(m0 + r1) * K + k0 + e1, (char*)As + c1 * 1024);
    gload_lds16(Bt + (size_t)(n0 + r0) * K + k0 + e0, (char*)Bs + c0 * 1024);
    gload_lds16(Bt + (size_t)(n0 + r1) * K + k0 + e1, (char*)Bs + c1 * 1024);
    __syncthreads();
    bf16x8 af[4], bfv[4];
    for (int m = 0; m < 4; ++m)
      af[m] = *reinterpret_cast<const bf16x8*>(&As[(wr * 64 + m * 16 + lid) * 32 + lgrp * 8]);
    for (int n = 0; n < 4; ++n)
      bfv[n] = *reinterpret_cast<const bf16x8*>(&Bs[(wc * 64 + n * 16 + lid) * 32 + lgrp * 8]);
    for (int m = 0; m < 4; ++m)
      for (int n = 0; n < 4; ++n)
        acc[m][n] = __builtin_amdgcn_mfma_f32_16x16x32_bf16(af[m], bfv[n], acc[m][n], 0, 0, 0);
  }

  // C frag layout: row = (lane>>4)*4 + r, col = lane&15
  if constexpr (SMODE == 2) {
    float* C = (float*)Cout;
    for (int m = 0; m < 4; ++m) {
      int rowb = m0 + wr * 64 + m * 16 + lgrp * 4;
      for (int n = 0; n < 4; ++n) {
        int col = n0 + wc * 64 + n * 16 + lid;
        for (int r = 0; r < 4; ++r)
          C[(size_t)(rowb + r) * 1024 + col] = acc[m][n][r];
      }
    }
  } else if constexpr (SMODE == 0 || SMODE == 3) {
    bf16* C = (bf16*)Cout;
    for (int m = 0; m < 4; ++m) {
      int rowb = m0 + wr * 64 + m * 16 + lgrp * 4;
      for (int n = 0; n < 4; ++n) {
        int col = n0 + wc * 64 + n * 16 + lid;
        int h = col >> 6, e = col & 63;
        for (int r = 0; r < 4; ++r) {
          int row = rowb + r;
          int b = row >> 11, s = row & 2047;
          int e2 = (SMODE == 3) ? (e ^ ((s & 7) << 3)) : e;
          C[(((size_t)b * 16 + h) * 2048 + s) * 64 + e2] = (bf16)acc[m][n][r];
        }
      }
    }
  } else {  // SMODE 1: V^T [B,H,64,S] swizzled; 4 consecutive s -> 8B store
    bf16* C = (bf16*)Cout;
    for (int m = 0; m < 4; ++m) {
      int rowb = m0 + wr * 64 + m * 16 + lgrp * 4;
      int b = rowb >> 11, s = rowb & 2047;
      for (int n = 0; n < 4; ++n) {
        int col = n0 + wc * 64 + n * 16 + lid;
        int h = col >> 6, e = col & 63;
        union { bf16 hv[4]; uint2 u; } tmp;
        for (int r = 0; r < 4; ++r) tmp.hv[r] = (bf16)acc[m][n][r];
        // s multiple of 4; XOR flips bits 3..5 -> 8B group stays contiguous
        bf16* dst = C + (((size_t)b * 16 + h) * 64 + e) * 2048 + (s ^ ((e & 7) << 3));
        *reinterpret_cast<uint2*>(dst) = tmp.u;
      }
    }
  }
}

// ---------------- flash attention ----------------
// Qh: [B,H,S,64] plain; Ksw: [B,H,S,64] row-swizzled; Vsw: [B,H,64,S] row-swizzled
// Ob: [B,S,H*64] bf16.  Block = 64 q-rows (4 waves x 16), KV tile = 64 keys,
// K/V staged cooperatively in LDS (double-buffered, global_load_lds prefetch).
__global__ __launch_bounds__(256) void k_flash(const bf16* __restrict__ Qh,
                                               const bf16* __restrict__ Ksw,
                                               const bf16* __restrict__ Vsw,
                                               const int* __restrict__ valid,
                                               bf16* __restrict__ Ob) {
  __shared__ __align__(16) char Ks[2][64 * 128];
  __shared__ __align__(16) char Vs[2][64 * 128];
  __shared__ __align__(16) char Plds[4][16 * 128];
  const int tid = threadIdx.x, lane = tid & 63, w = tid >> 6;
  const int lgrp = lane >> 4, lid = lane & 15;
  const int blk = blockIdx.x;
  const int qt = blk & 31, bh = blk >> 5;  // consecutive blocks share (b,h) -> L2 reuse
  const int b = bh >> 4, h = bh & 15;
  const int s0 = qt * 64 + w * 16;
  const bf16* Qp = Qh + ((size_t)bh * 2048 + s0) * 64;
  const bf16* Kp = Ksw + (size_t)bh * 2048 * 64;
  const bf16* Vp = Vsw + (size_t)bh * 64 * 2048;
  const int vl = valid[b];
  const int nt = (vl + 63) >> 6;

  // staging geometry: wave w stages LDS rows [16w,16w+16) for both K and V
  const int sub = lane >> 3, col8 = (lane & 7) * 8;
  const int sr0 = 16 * w + sub, sr1 = 16 * w + 8 + sub;

  // prologue: stage tile 0 into buffer 0
  gload_lds16(Kp + (size_t)sr0 * 64 + col8, &Ks[0][(16 * w) * 128]);
  gload_lds16(Kp + (size_t)sr1 * 64 + col8, &Ks[0][(16 * w + 8) * 128]);
  gload_lds16(Vp + (size_t)sr0 * 2048 + col8, &Vs[0][(16 * w) * 128]);
  gload_lds16(Vp + (size_t)sr1 * 2048 + col8, &Vs[0][(16 * w + 8) * 128]);

  // Q A-frags (row=lid, k=lgrp*8+j)
  bf16x8 aq0 = *reinterpret_cast<const bf16x8*>(Qp + lid * 64 + lgrp * 8);
  bf16x8 aq1 = *reinterpret_cast<const bf16x8*>(Qp + lid * 64 + 32 + lgrp * 8);

  f32x4 Of[4] = {};
  float mrow[4] = {-1e30f, -1e30f, -1e30f, -1e30f};
  float lrow[4] = {0.f, 0.f, 0.f, 0.f};
  char* Pw = &Plds[w][0];

  int cur = 0;
  for (int t = 0; t < nt; ++t) {
    const int t0 = t * 64;
    __syncthreads();  // drains vmcnt: buf[cur] staged & visible to all waves
    if (t + 1 < nt) {  // prefetch next tile (async, flies under compute)
      const int t1 = t0 + 64;
      gload_lds16(Kp + (size_t)(t1 + sr0) * 64 + col8, &Ks[cur ^ 1][(16 * w) * 128]);
      gload_lds16(Kp + (size_t)(t1 + sr1) * 64 + col8, &Ks[cur ^ 1][(16 * w + 8) * 128]);
      gload_lds16(Vp + (size_t)sr0 * 2048 + t1 + col8, &Vs[cur ^ 1][(16 * w) * 128]);
      gload_lds16(Vp + (size_t)sr1 * 2048 + t1 + col8, &Vs[cur ^ 1][(16 * w + 8) * 128]);
    }
    // scores S[16q][64k] = Q * K^T from LDS (swizzled reads)
    f32x4 sc[4] = {};
#pragma unroll
    for (int ct = 0; ct < 4; ++ct) {
      const int row = ct * 16 + lid;
      const char* kb = &Ks[cur][row * 128];
      const int msk = (row & 7) << 4;
      bf16x8 bk0 = *reinterpret_cast<const bf16x8*>(kb + ((lgrp * 16) ^ msk));
      bf16x8 bk1 = *reinterpret_cast<const bf16x8*>(kb + ((64 + lgrp * 16) ^ msk));
      sc[ct] = __builtin_amdgcn_mfma_f32_16x16x32_bf16(aq0, bk0, sc[ct], 0, 0, 0);
      sc[ct] = __builtin_amdgcn_mfma_f32_16x16x32_bf16(aq1, bk1, sc[ct], 0, 0, 0);
    }
    // scale + padding mask
#pragma unroll
    for (int ct = 0; ct < 4; ++ct) {
      const bool masked = (t0 + ct * 16 + lid) >= vl;
#pragma unroll
      for (int r = 0; r < 4; ++r)
        sc[ct][r] = masked ? -1e30f : sc[ct][r] * 0.125f;
    }
    // online max (critical path to exp)
    float scale[4];
#pragma unroll
    for (int r = 0; r < 4; ++r) {
      float vm = fmaxf(fmaxf(sc[0][r], sc[1][r]), fmaxf(sc[2][r], sc[3][r]));
      vm = fmaxf(vm, __shfl_xor(vm, 1));
      vm = fmaxf(vm, __shfl_xor(vm, 2));
      vm = fmaxf(vm, __shfl_xor(vm, 4));
      vm = fmaxf(vm, __shfl_xor(vm, 8));
      float mnew = fmaxf(mrow[r], vm);
      scale[r] = __expf(mrow[r] - mnew);
      mrow[r] = mnew;
    }
#pragma unroll
    for (int ct = 0; ct < 4; ++ct)
#pragma unroll
      for (int r = 0; r < 4; ++r)
        sc[ct][r] = __expf(sc[ct][r] - mrow[r]);
    // P: C-layout -> LDS (swizzled) -> A-layout (within-wave)
#pragma unroll
    for (int ct = 0; ct < 4; ++ct)
#pragma unroll
      for (int r = 0; r < 4; ++r) {
        const int row = lgrp * 4 + r;
        const int cb = (ct * 16 + lid) * 2;
        *reinterpret_cast<bf16*>(Pw + row * 128 + (cb ^ ((row & 7) << 4))) = (bf16)sc[ct][r];
      }
    // Of rescale fills the LDS-write drain window
#pragma unroll
    for (int f = 0; f < 4; ++f)
#pragma unroll
      for (int r = 0; r < 4; ++r)
        Of[f][r] *= scale[r];
    asm volatile("s_waitcnt lgkmcnt(0)" ::: "memory");
    bf16x8 pa0 = *reinterpret_cast<const bf16x8*>(Pw + lid * 128 + ((lgrp * 16) ^ ((lid & 7) << 4)));
    bf16x8 pa1 = *reinterpret_cast<const bf16x8*>(Pw + lid * 128 + ((64 + lgrp * 16) ^ ((lid & 7) << 4)));
    // PV from LDS V^T tile (swizzled reads)
#pragma unroll
    for (int f = 0; f < 4; ++f) {
      const int row = f * 16 + lid;
      const char* vb = &Vs[cur][row * 128];
      const int msk = (row & 7) << 4;
      bf16x8 bv0 = *reinterpret_cast<const bf16x8*>(vb + ((lgrp * 16) ^ msk));
      bf16x8 bv1 = *reinterpret_cast<const bf16x8*>(vb + ((64 + lgrp * 16) ^ msk));
      Of[f] = __builtin_amdgcn_mfma_f32_16x16x32_bf16(pa0, bv0, Of[f], 0, 0, 0);
      Of[f] = __builtin_amdgcn_mfma_f32_16x16x32_bf16(pa1, bv1, Of[f], 0, 0, 0);
    }
    // l update AFTER PV issue: off the MFMA critical path
#pragma unroll
    for (int r = 0; r < 4; ++r) {
      float s = (sc[0][r] + sc[1][r]) + (sc[2][r] + sc[3][r]);
      s += __shfl_xor(s, 1);
      s += __shfl_xor(s, 2);
      s += __shfl_xor(s, 4);
      s += __shfl_xor(s, 8);
      lrow[r] = lrow[r] * scale[r] + s;
    }
    cur ^= 1;
  }
  // epilogue
  bf16* Op = Ob + ((size_t)b * 2048 + s0) * 1024 + h * 64;
#pragma unroll
  for (int r = 0; r < 4; ++r) {
    float inv = 1.f / lrow[r];
#pragma unroll
    for (int f = 0; f < 4; ++f)
      Op[(size_t)(lgrp * 4 + r) * 1024 + f * 16 + lid] = (bf16)(Of[f][r] * inv);
  }
}

// ---------------- launch ----------------
extern "C" void kernel_launch(void* const* d_in, const int* in_sizes, int n_in,
                              void* d_out, int out_size, void* d_ws, size_t ws_size,
                              hipStream_t stream) {
  const float* q = (const float*)d_in[0];
  const float* k = (const float*)d_in[1];
  const float* v = (const float*)d_in[2];
  const int* vl = (const int*)d_in[3];
  const float* Wq = (const float*)d_in[4];
  const float* Wk = (const float*)d_in[5];
  const float* Wv = (const float*)d_in[6];
  const float* Wo = (const float*)d_in[7];

  char* ws = (char*)d_ws;
  const size_t SZW = (size_t)1024 * 1024 * 2;  // 2MB
  const size_t SZT = (size_t)8192 * 1024 * 2;  // 16MB
  bf16* WqT = (bf16*)(ws);
  bf16* WkT = (bf16*)(ws + SZW);
  bf16* WvT = (bf16*)(ws + 2 * SZW);
  bf16* WoT = (bf16*)(ws + 3 * SZW);
  bf16* Qh  = (bf16*)(ws + 4 * SZW);
  bf16* Kh  = (bf16*)(ws + 4 * SZW + SZT);
  bf16* Vt  = (bf16*)(ws + 4 * SZW + 2 * SZT);
  bf16* qb  = (bf16*)(ws + 4 * SZW + 3 * SZT);
  bf16* kb  = (bf16*)(ws + 4 * SZW + 4 * SZT);
  bf16* vb  = (bf16*)(ws + 4 * SZW + 5 * SZT);
  bf16* attnb = qb;  // qb dead after Q projection

  k_cvt_bf16<<<4096, 256, 0, stream>>>(q, qb, 1 << 20);
  k_cvt_bf16<<<4096, 256, 0, stream>>>(k, kb, 1 << 20);
  k_cvt_bf16<<<4096, 256, 0, stream>>>(v, vb, 1 << 20);
  k_cvt_wqkv<<<4096, 256, 0, stream>>>(Wq, WqT);
  k_cvt_wqkv<<<4096, 256, 0, stream>>>(Wk, WkT);
  k_cvt_wqkv<<<4096, 256, 0, stream>>>(Wv, WvT);
  k_cvt_wo<<<4096, 256, 0, stream>>>(Wo, WoT);

  dim3 gg(64, 8);
  k_gemm<0><<<gg, 256, 0, stream>>>(qb, WqT, Qh);   // Q plain
  k_gemm<3><<<gg, 256, 0, stream>>>(kb, WkT, Kh);   // K swizzled
  k_gemm<1><<<gg, 256, 0, stream>>>(vb, WvT, Vt);   // V^T swizzled
  k_flash<<<2048, 256, 0, stream>>>(Qh, Kh, Vt, vl, attnb);
  k_gemm<2><<<gg, 256, 0, stream>>>(attnb, WoT, d_out);
}

// Round 4
// 224.332 us; speedup vs baseline: 2.2761x; 1.2349x over previous
//
#include <hip/hip_runtime.h>
#include <hip/hip_bf16.h>

typedef __bf16 bf16;
typedef __attribute__((ext_vector_type(8))) __bf16 bf16x8;
typedef __attribute__((ext_vector_type(4))) float f32x4;

#define DEV __device__ __forceinline__

DEV float fexp2(float x) {
#if __has_builtin(__builtin_amdgcn_exp2f)
  return __builtin_amdgcn_exp2f(x);
#else
  return exp2f(x);
#endif
}

// async global->LDS, 16B per lane; LDS dest = wave-uniform base + lane*16
DEV void gload_lds16(const void* g, void* l) {
  __builtin_amdgcn_global_load_lds(
      (__attribute__((address_space(1))) void*)(g),
      (__attribute__((address_space(3))) void*)(l), 16, 0, 0);
}

// ---------------- fused conversion kernels ----------------
// activations fp32 -> bf16 (q,k,v in one launch; 8 elems/thread)
__global__ void k_cvt_act(const float* __restrict__ q, const float* __restrict__ k,
                          const float* __restrict__ v, bf16* __restrict__ qb,
                          bf16* __restrict__ kb, bf16* __restrict__ vb) {
  const int bid = blockIdx.x;          // 0..12287
  const int which = bid >> 12;         // 4096 blocks per tensor
  const float* in = which == 0 ? q : which == 1 ? k : v;
  bf16* out = which == 0 ? qb : which == 1 ? kb : vb;
  const int i = (bid & 4095) * 256 + threadIdx.x;  // < 1<<20 groups of 8
  const float4* p = reinterpret_cast<const float4*>(in) + (size_t)i * 2;
  float4 a = p[0], b = p[1];
  bf16x8 o;
  o[0] = (bf16)a.x; o[1] = (bf16)a.y; o[2] = (bf16)a.z; o[3] = (bf16)a.w;
  o[4] = (bf16)b.x; o[5] = (bf16)b.y; o[6] = (bf16)b.z; o[7] = (bf16)b.w;
  *reinterpret_cast<bf16x8*>(out + (size_t)i * 8) = o;
}

// weights: Wq/Wk/Wv [16,1024,64] -> WqkvT [3072][1024] (Wq scaled by 0.125*log2e);
// Wo [1024,1024] -> WoT [1024][1024] transposed. One launch, 4M threads.
__global__ void k_cvt_w(const float* __restrict__ Wq, const float* __restrict__ Wk,
                        const float* __restrict__ Wv, const float* __restrict__ Wo,
                        bf16* __restrict__ WqkvT, bf16* __restrict__ WoT) {
  const int idx = blockIdx.x * blockDim.x + threadIdx.x;  // 0..4M
  const int which = idx >> 20, r = idx & ((1 << 20) - 1);
  if (which < 3) {
    const float* W = which == 0 ? Wq : which == 1 ? Wk : Wv;
    const int d = r & 1023, n = r >> 10;
    float val = W[((size_t)(n >> 6) << 16) + (size_t)d * 64 + (n & 63)];
    if (which == 0) val *= 0.180336880f;  // 1/sqrt(64) * log2(e): scores in exp2 domain
    WqkvT[((size_t)which << 20) + r] = (bf16)val;
  } else {
    const int kk = r & 1023, n = r >> 10;
    WoT[r] = (bf16)Wo[(size_t)kk * 1024 + n];
  }
}

// ---------------- merged QKV projection GEMM ----------------
// grid (64, 24): proj = n-block/8 selects {Q,K,V}; per-proj A pointer.
// Q -> [B,H,S,64] plain; K -> [B,H,S,64] row-swizzled; V -> [B,H,64,S] row-swizzled.
// Swizzle: elem e of 64-elem row r stored at e^((r&7)<<3) (both-sides rule #21).
__global__ __launch_bounds__(256) void k_gemm_qkv(const bf16* __restrict__ qA,
                                                  const bf16* __restrict__ kA,
                                                  const bf16* __restrict__ vA,
                                                  const bf16* __restrict__ Wt,
                                                  bf16* __restrict__ Qh,
                                                  bf16* __restrict__ Kh,
                                                  bf16* __restrict__ Vt) {
  constexpr int K = 1024;
  __shared__ __align__(16) bf16 As[128 * 32];
  __shared__ __align__(16) bf16 Bs[128 * 32];
  const int tid = threadIdx.x;
  const int lane = tid & 63, w = tid >> 6;
  const int wr = w >> 1, wc = w & 1;
  const int lgrp = lane >> 4, lid = lane & 15;
  const int m0 = blockIdx.x * 128;
  const int n0g = blockIdx.y * 128;
  const int proj = n0g >> 10, n0 = n0g & 1023;
  const bf16* A = proj == 0 ? qA : proj == 1 ? kA : vA;
  const bf16* Bt = Wt + (size_t)n0g * K;  // rows [n0g, n0g+128) of [3072][1024]

  f32x4 acc[4][4] = {};

  const int c0 = w * 2, c1 = w * 2 + 1;
  const int bo0 = c0 * 1024 + lane * 16, bo1 = c1 * 1024 + lane * 16;
  const int r0 = bo0 >> 6, e0 = (bo0 & 63) >> 1;
  const int r1 = bo1 >> 6, e1 = (bo1 & 63) >> 1;

  for (int k0 = 0; k0 < K; k0 += 32) {
    __syncthreads();
    gload_lds16(A + (size_t)(m0 + r0) * K + k0 + e0, (char*)As + c0 * 1024);
    gload_lds16(A + (size_t)(m0 + r1) * K + k0 + e1, (char*)As + c1 * 1024);
    gload_lds16(Bt + (size_t)r0 * K + k0 + e0, (char*)Bs + c0 * 1024);
    gload_lds16(Bt + (size_t)r1 * K + k0 + e1, (char*)Bs + c1 * 1024);
    __syncthreads();
    bf16x8 af[4], bfv[4];
    for (int m = 0; m < 4; ++m)
      af[m] = *reinterpret_cast<const bf16x8*>(&As[(wr * 64 + m * 16 + lid) * 32 + lgrp * 8]);
    for (int n = 0; n < 4; ++n)
      bfv[n] = *reinterpret_cast<const bf16x8*>(&Bs[(wc * 64 + n * 16 + lid) * 32 + lgrp * 8]);
    for (int m = 0; m < 4; ++m)
      for (int n = 0; n < 4; ++n)
        acc[m][n] = __builtin_amdgcn_mfma_f32_16x16x32_bf16(af[m], bfv[n], acc[m][n], 0, 0, 0);
  }

  // C frag layout: row = (lane>>4)*4 + r, col = lane&15
  if (proj == 0) {  // Q plain [B,H,S,64]
    for (int m = 0; m < 4; ++m) {
      int rowb = m0 + wr * 64 + m * 16 + lgrp * 4;
      for (int n = 0; n < 4; ++n) {
        int col = n0 + wc * 64 + n * 16 + lid;
        int h = col >> 6, e = col & 63;
        for (int r = 0; r < 4; ++r) {
          int row = rowb + r;
          int b = row >> 11, s = row & 2047;
          Qh[(((size_t)b * 16 + h) * 2048 + s) * 64 + e] = (bf16)acc[m][n][r];
        }
      }
    }
  } else if (proj == 1) {  // K row-swizzled [B,H,S,64]
    for (int m = 0; m < 4; ++m) {
      int rowb = m0 + wr * 64 + m * 16 + lgrp * 4;
      for (int n = 0; n < 4; ++n) {
        int col = n0 + wc * 64 + n * 16 + lid;
        int h = col >> 6, e = col & 63;
        for (int r = 0; r < 4; ++r) {
          int row = rowb + r;
          int b = row >> 11, s = row & 2047;
          Kh[(((size_t)b * 16 + h) * 2048 + s) * 64 + (e ^ ((s & 7) << 3))] = (bf16)acc[m][n][r];
        }
      }
    }
  } else {  // V^T row-swizzled [B,H,64,S]; 4 consecutive s -> packed 8B store
    for (int m = 0; m < 4; ++m) {
      int rowb = m0 + wr * 64 + m * 16 + lgrp * 4;
      int b = rowb >> 11, s = rowb & 2047;
      for (int n = 0; n < 4; ++n) {
        int col = n0 + wc * 64 + n * 16 + lid;
        int h = col >> 6, e = col & 63;
        union { bf16 hv[4]; uint2 u; } tmp;
        for (int r = 0; r < 4; ++r) tmp.hv[r] = (bf16)acc[m][n][r];
        bf16* dst = Vt + (((size_t)b * 16 + h) * 64 + e) * 2048 + (s ^ ((e & 7) << 3));
        *reinterpret_cast<uint2*>(dst) = tmp.u;
      }
    }
  }
}

// ---------------- output-projection GEMM (f32 out) ----------------
__global__ __launch_bounds__(256) void k_gemm_out(const bf16* __restrict__ A,
                                                  const bf16* __restrict__ Bt,
                                                  float* __restrict__ C) {
  constexpr int K = 1024;
  __shared__ __align__(16) bf16 As[128 * 32];
  __shared__ __align__(16) bf16 Bs[128 * 32];
  const int tid = threadIdx.x;
  const int lane = tid & 63, w = tid >> 6;
  const int wr = w >> 1, wc = w & 1;
  const int lgrp = lane >> 4, lid = lane & 15;
  const int m0 = blockIdx.x * 128, n0 = blockIdx.y * 128;

  f32x4 acc[4][4] = {};
  const int c0 = w * 2, c1 = w * 2 + 1;
  const int bo0 = c0 * 1024 + lane * 16, bo1 = c1 * 1024 + lane * 16;
  const int r0 = bo0 >> 6, e0 = (bo0 & 63) >> 1;
  const int r1 = bo1 >> 6, e1 = (bo1 & 63) >> 1;

  for (int k0 = 0; k0 < K; k0 += 32) {
    __syncthreads();
    gload_lds16(A + (size_t)(m0 + r0) * K + k0 + e0, (char*)As + c0 * 1024);
    gload_lds16(A + (size_t)(m0 + r1) * K + k0 + e1, (char*)As + c1 * 1024);
    gload_lds16(Bt + (size_t)(n0 + r0) * K + k0 + e0, (char*)Bs + c0 * 1024);
    gload_lds16(Bt + (size_t)(n0 + r1) * K + k0 + e1, (char*)Bs + c1 * 1024);
    __syncthreads();
    bf16x8 af[4], bfv[4];
    for (int m = 0; m < 4; ++m)
      af[m] = *reinterpret_cast<const bf16x8*>(&As[(wr * 64 + m * 16 + lid) * 32 + lgrp * 8]);
    for (int n = 0; n < 4; ++n)
      bfv[n] = *reinterpret_cast<const bf16x8*>(&Bs[(wc * 64 + n * 16 + lid) * 32 + lgrp * 8]);
    for (int m = 0; m < 4; ++m)
      for (int n = 0; n < 4; ++n)
        acc[m][n] = __builtin_amdgcn_mfma_f32_16x16x32_bf16(af[m], bfv[n], acc[m][n], 0, 0, 0);
  }
  for (int m = 0; m < 4; ++m) {
    int rowb = m0 + wr * 64 + m * 16 + lgrp * 4;
    for (int n = 0; n < 4; ++n) {
      int col = n0 + wc * 64 + n * 16 + lid;
      for (int r = 0; r < 4; ++r)
        C[(size_t)(rowb + r) * 1024 + col] = acc[m][n][r];
    }
  }
}

// ---------------- flash attention ----------------
// Qh plain (pre-scaled into exp2 domain via Wq); Ksw/Vsw row-swizzled.
// Block = 64 q-rows (4 waves x 16), KV tile = 64 keys, LDS double-buffered.
// Defer-max (THR=8 base-2): common path has NO shfl; l-reduce deferred to epilogue.
__global__ __launch_bounds__(256) void k_flash(const bf16* __restrict__ Qh,
                                               const bf16* __restrict__ Ksw,
                                               const bf16* __restrict__ Vsw,
                                               const int* __restrict__ valid,
                                               bf16* __restrict__ Ob) {
  __shared__ __align__(16) char Ks[2][64 * 128];
  __shared__ __align__(16) char Vs[2][64 * 128];
  __shared__ __align__(16) char Plds[4][16 * 128];
  const int tid = threadIdx.x, lane = tid & 63, w = tid >> 6;
  const int lgrp = lane >> 4, lid = lane & 15;
  const int blk = blockIdx.x;
  const int qt = blk & 31, bh = blk >> 5;  // consecutive blocks share (b,h) -> L2 reuse
  const int b = bh >> 4, h = bh & 15;
  const int s0 = qt * 64 + w * 16;
  const bf16* Qp = Qh + ((size_t)bh * 2048 + s0) * 64;
  const bf16* Kp = Ksw + (size_t)bh * 2048 * 64;
  const bf16* Vp = Vsw + (size_t)bh * 64 * 2048;
  const int vl = valid[b];
  const int nt = (vl + 63) >> 6;
  const int full = vl >> 6;  // tiles with no masked key

  const int sub = lane >> 3, col8 = (lane & 7) * 8;
  const int sr0 = 16 * w + sub, sr1 = 16 * w + 8 + sub;

  gload_lds16(Kp + (size_t)sr0 * 64 + col8, &Ks[0][(16 * w) * 128]);
  gload_lds16(Kp + (size_t)sr1 * 64 + col8, &Ks[0][(16 * w + 8) * 128]);
  gload_lds16(Vp + (size_t)sr0 * 2048 + col8, &Vs[0][(16 * w) * 128]);
  gload_lds16(Vp + (size_t)sr1 * 2048 + col8, &Vs[0][(16 * w + 8) * 128]);

  bf16x8 aq0 = *reinterpret_cast<const bf16x8*>(Qp + lid * 64 + lgrp * 8);
  bf16x8 aq1 = *reinterpret_cast<const bf16x8*>(Qp + lid * 64 + 32 + lgrp * 8);

  f32x4 Of[4] = {};
  float mrow[4] = {-1e30f, -1e30f, -1e30f, -1e30f};
  float lpart[4] = {0.f, 0.f, 0.f, 0.f};
  char* Pw = &Plds[w][0];

  int cur = 0;
  for (int t = 0; t < nt; ++t) {
    const int t0 = t * 64;
    __syncthreads();  // buf[cur] staged & visible (vmcnt drained at barrier)
    if (t + 1 < nt) {
      const int t1 = t0 + 64;
      gload_lds16(Kp + (size_t)(t1 + sr0) * 64 + col8, &Ks[cur ^ 1][(16 * w) * 128]);
      gload_lds16(Kp + (size_t)(t1 + sr1) * 64 + col8, &Ks[cur ^ 1][(16 * w + 8) * 128]);
      gload_lds16(Vp + (size_t)sr0 * 2048 + t1 + col8, &Vs[cur ^ 1][(16 * w) * 128]);
      gload_lds16(Vp + (size_t)sr1 * 2048 + t1 + col8, &Vs[cur ^ 1][(16 * w + 8) * 128]);
    }
    // scores (exp2 domain, scale pre-folded into Wq)
    f32x4 sc[4] = {};
#pragma unroll
    for (int ct = 0; ct < 4; ++ct) {
      const int row = ct * 16 + lid;
      const char* kb = &Ks[cur][row * 128];
      const int msk = (row & 7) << 4;
      bf16x8 bk0 = *reinterpret_cast<const bf16x8*>(kb + ((lgrp * 16) ^ msk));
      bf16x8 bk1 = *reinterpret_cast<const bf16x8*>(kb + ((64 + lgrp * 16) ^ msk));
      sc[ct] = __builtin_amdgcn_mfma_f32_16x16x32_bf16(aq0, bk0, sc[ct], 0, 0, 0);
      sc[ct] = __builtin_amdgcn_mfma_f32_16x16x32_bf16(aq1, bk1, sc[ct], 0, 0, 0);
    }
    if (t >= full) {  // only the single partial tile pays masking cost
#pragma unroll
      for (int ct = 0; ct < 4; ++ct) {
        const bool masked = (t0 + ct * 16 + lid) >= vl;
#pragma unroll
        for (int r = 0; r < 4; ++r)
          sc[ct][r] = masked ? -1e30f : sc[ct][r];
      }
    }
    // defer-max check: per-lane partial row maxes, no cross-lane traffic
    float vmp[4];
#pragma unroll
    for (int r = 0; r < 4; ++r)
      vmp[r] = fmaxf(fmaxf(sc[0][r], sc[1][r]), fmaxf(sc[2][r], sc[3][r]));
    const int grow = (vmp[0] > mrow[0] + 8.f) | (vmp[1] > mrow[1] + 8.f) |
                     (vmp[2] > mrow[2] + 8.f) | (vmp[3] > mrow[3] + 8.f);
    if (__any(grow)) {  // rare after warm-up: full row max + rescale
      float scale[4];
#pragma unroll
      for (int r = 0; r < 4; ++r) {
        float vm = vmp[r];
        vm = fmaxf(vm, __shfl_xor(vm, 1));
        vm = fmaxf(vm, __shfl_xor(vm, 2));
        vm = fmaxf(vm, __shfl_xor(vm, 4));
        vm = fmaxf(vm, __shfl_xor(vm, 8));
        float mnew = fmaxf(mrow[r], vm);
        scale[r] = fexp2(mrow[r] - mnew);
        mrow[r] = mnew;
        lpart[r] *= scale[r];
      }
#pragma unroll
      for (int f = 0; f < 4; ++f)
#pragma unroll
        for (int r = 0; r < 4; ++r)
          Of[f][r] *= scale[r];
    }
#pragma unroll
    for (int ct = 0; ct < 4; ++ct)
#pragma unroll
      for (int r = 0; r < 4; ++r)
        sc[ct][r] = fexp2(sc[ct][r] - mrow[r]);  // bounded by 2^8
    // P: C-layout -> LDS (swizzled) -> A-layout (within-wave)
#pragma unroll
    for (int ct = 0; ct < 4; ++ct)
#pragma unroll
      for (int r = 0; r < 4; ++r) {
        const int row = lgrp * 4 + r;
        const int cb = (ct * 16 + lid) * 2;
        *reinterpret_cast<bf16*>(Pw + row * 128 + (cb ^ ((row & 7) << 4))) = (bf16)sc[ct][r];
      }
    asm volatile("s_waitcnt lgkmcnt(0)" ::: "memory");
    bf16x8 pa0 = *reinterpret_cast<const bf16x8*>(Pw + lid * 128 + ((lgrp * 16) ^ ((lid & 7) << 4)));
    bf16x8 pa1 = *reinterpret_cast<const bf16x8*>(Pw + lid * 128 + ((64 + lgrp * 16) ^ ((lid & 7) << 4)));
#pragma unroll
    for (int f = 0; f < 4; ++f) {
      const int row = f * 16 + lid;
      const char* vb = &Vs[cur][row * 128];
      const int msk = (row & 7) << 4;
      bf16x8 bv0 = *reinterpret_cast<const bf16x8*>(vb + ((lgrp * 16) ^ msk));
      bf16x8 bv1 = *reinterpret_cast<const bf16x8*>(vb + ((64 + lgrp * 16) ^ msk));
      Of[f] = __builtin_amdgcn_mfma_f32_16x16x32_bf16(pa0, bv0, Of[f], 0, 0, 0);
      Of[f] = __builtin_amdgcn_mfma_f32_16x16x32_bf16(pa1, bv1, Of[f], 0, 0, 0);
    }
    // per-lane partial l accumulation (cross-lane reduce deferred to epilogue)
#pragma unroll
    for (int r = 0; r < 4; ++r)
      lpart[r] += (sc[0][r] + sc[1][r]) + (sc[2][r] + sc[3][r]);
    cur ^= 1;
  }
  // epilogue: reduce l across the 16-lane col group, normalize, store
  bf16* Op = Ob + ((size_t)b * 2048 + s0) * 1024 + h * 64;
#pragma unroll
  for (int r = 0; r < 4; ++r) {
    float l = lpart[r];
    l += __shfl_xor(l, 1);
    l += __shfl_xor(l, 2);
    l += __shfl_xor(l, 4);
    l += __shfl_xor(l, 8);
    float inv = 1.f / l;
#pragma unroll
    for (int f = 0; f < 4; ++f)
      Op[(size_t)(lgrp * 4 + r) * 1024 + f * 16 + lid] = (bf16)(Of[f][r] * inv);
  }
}

// ---------------- launch ----------------
extern "C" void kernel_launch(void* const* d_in, const int* in_sizes, int n_in,
                              void* d_out, int out_size, void* d_ws, size_t ws_size,
                              hipStream_t stream) {
  const float* q = (const float*)d_in[0];
  const float* k = (const float*)d_in[1];
  const float* v = (const float*)d_in[2];
  const int* vl = (const int*)d_in[3];
  const float* Wq = (const float*)d_in[4];
  const float* Wk = (const float*)d_in[5];
  const float* Wv = (const float*)d_in[6];
  const float* Wo = (const float*)d_in[7];

  char* ws = (char*)d_ws;
  const size_t SZW = (size_t)1024 * 1024 * 2;  // 2MB per weight matrix
  const size_t SZT = (size_t)8192 * 1024 * 2;  // 16MB per bf16 activation tensor
  bf16* WqkvT = (bf16*)(ws);                   // 6MB [3072][1024]
  bf16* WoT = (bf16*)(ws + 3 * SZW);
  bf16* Qh  = (bf16*)(ws + 4 * SZW);
  bf16* Kh  = (bf16*)(ws + 4 * SZW + SZT);
  bf16* Vt  = (bf16*)(ws + 4 * SZW + 2 * SZT);
  bf16* qb  = (bf16*)(ws + 4 * SZW + 3 * SZT);
  bf16* kb  = (bf16*)(ws + 4 * SZW + 4 * SZT);
  bf16* vb  = (bf16*)(ws + 4 * SZW + 5 * SZT);
  bf16* attnb = qb;  // qb dead after projections

  k_cvt_act<<<12288, 256, 0, stream>>>(q, k, v, qb, kb, vb);
  k_cvt_w<<<16384, 256, 0, stream>>>(Wq, Wk, Wv, Wo, WqkvT, WoT);
  dim3 gq(64, 24);
  k_gemm_qkv<<<gq, 256, 0, stream>>>(qb, kb, vb, WqkvT, Qh, Kh, Vt);
  k_flash<<<2048, 256, 0, stream>>>(Qh, Kh, Vt, vl, attnb);
  dim3 go(64, 8);
  k_gemm_out<<<go, 256, 0, stream>>>(attnb, WoT, (float*)d_out);
}

// Round 5
// 205.790 us; speedup vs baseline: 2.4812x; 1.0901x over previous
//
#include <hip/hip_runtime.h>
#include <hip/hip_bf16.h>

typedef __bf16 bf16;
typedef __attribute__((ext_vector_type(8))) __bf16 bf16x8;
typedef __attribute__((ext_vector_type(4))) float f32x4;

#define DEV __device__ __forceinline__

DEV float fexp2(float x) {
#if __has_builtin(__builtin_amdgcn_exp2f)
  return __builtin_amdgcn_exp2f(x);
#else
  return exp2f(x);
#endif
}

// async global->LDS, 16B per lane; LDS dest = wave-uniform base + lane*16
DEV void gload_lds16(const void* g, void* l) {
  __builtin_amdgcn_global_load_lds(
      (__attribute__((address_space(1))) void*)(g),
      (__attribute__((address_space(3))) void*)(l), 16, 0, 0);
}

// ---------------- fused conversion kernels ----------------
// activations fp32 -> bf16 (q,k,v in one launch; 8 elems/thread)
__global__ void k_cvt_act(const float* __restrict__ q, const float* __restrict__ k,
                          const float* __restrict__ v, bf16* __restrict__ qb,
                          bf16* __restrict__ kb, bf16* __restrict__ vb) {
  const int bid = blockIdx.x;          // 0..12287
  const int which = bid >> 12;         // 4096 blocks per tensor
  const float* in = which == 0 ? q : which == 1 ? k : v;
  bf16* out = which == 0 ? qb : which == 1 ? kb : vb;
  const int i = (bid & 4095) * 256 + threadIdx.x;  // < 1<<20 groups of 8
  const float4* p = reinterpret_cast<const float4*>(in) + (size_t)i * 2;
  float4 a = p[0], b = p[1];
  bf16x8 o;
  o[0] = (bf16)a.x; o[1] = (bf16)a.y; o[2] = (bf16)a.z; o[3] = (bf16)a.w;
  o[4] = (bf16)b.x; o[5] = (bf16)b.y; o[6] = (bf16)b.z; o[7] = (bf16)b.w;
  *reinterpret_cast<bf16x8*>(out + (size_t)i * 8) = o;
}

// weights: Wq/Wk/Wv [16,1024,64] -> WqkvT [3072][1024] (Wq scaled by 0.125*log2e);
// Wo [1024,1024] -> WoT [1024][1024] transposed. One launch, 4M threads.
__global__ void k_cvt_w(const float* __restrict__ Wq, const float* __restrict__ Wk,
                        const float* __restrict__ Wv, const float* __restrict__ Wo,
                        bf16* __restrict__ WqkvT, bf16* __restrict__ WoT) {
  const int idx = blockIdx.x * blockDim.x + threadIdx.x;  // 0..4M
  const int which = idx >> 20, r = idx & ((1 << 20) - 1);
  if (which < 3) {
    const float* W = which == 0 ? Wq : which == 1 ? Wk : Wv;
    const int d = r & 1023, n = r >> 10;
    float val = W[((size_t)(n >> 6) << 16) + (size_t)d * 64 + (n & 63)];
    if (which == 0) val *= 0.180336880f;  // 1/sqrt(64) * log2(e): scores in exp2 domain
    WqkvT[((size_t)which << 20) + r] = (bf16)val;
  } else {
    const int kk = r & 1023, n = r >> 10;
    WoT[r] = (bf16)Wo[(size_t)kk * 1024 + n];
  }
}

// ---------------- merged QKV projection GEMM ----------------
// grid (64, 24): proj = n-block/8 selects {Q,K,V}; per-proj A pointer.
// Q -> [B,H,S,64] plain; K -> [B,H,S,64] row-swizzled; V -> [B,H,64,S] row-swizzled.
// Swizzle: elem e of 64-elem row r stored at e^((r&7)<<3) (both-sides rule #21).
__global__ __launch_bounds__(256) void k_gemm_qkv(const bf16* __restrict__ qA,
                                                  const bf16* __restrict__ kA,
                                                  const bf16* __restrict__ vA,
                                                  const bf16* __restrict__ Wt,
                                                  bf16* __restrict__ Qh,
                                                  bf16* __restrict__ Kh,
                                                  bf16* __restrict__ Vt) {
  constexpr int K = 1024;
  __shared__ __align__(16) bf16 As[128 * 32];
  __shared__ __align__(16) bf16 Bs[128 * 32];
  const int tid = threadIdx.x;
  const int lane = tid & 63, w = tid >> 6;
  const int wr = w >> 1, wc = w & 1;
  const int lgrp = lane >> 4, lid = lane & 15;
  const int m0 = blockIdx.x * 128;
  const int n0g = blockIdx.y * 128;
  const int proj = n0g >> 10, n0 = n0g & 1023;
  const bf16* A = proj == 0 ? qA : proj == 1 ? kA : vA;
  const bf16* Bt = Wt + (size_t)n0g * K;  // rows [n0g, n0g+128) of [3072][1024]

  f32x4 acc[4][4] = {};

  const int c0 = w * 2, c1 = w * 2 + 1;
  const int bo0 = c0 * 1024 + lane * 16, bo1 = c1 * 1024 + lane * 16;
  const int r0 = bo0 >> 6, e0 = (bo0 & 63) >> 1;
  const int r1 = bo1 >> 6, e1 = (bo1 & 63) >> 1;

  for (int k0 = 0; k0 < K; k0 += 32) {
    __syncthreads();
    gload_lds16(A + (size_t)(m0 + r0) * K + k0 + e0, (char*)As + c0 * 1024);
    gload_lds16(A + (size_t)(m0 + r1) * K + k0 + e1, (char*)As + c1 * 1024);
    gload_lds16(Bt + (size_t)r0 * K + k0 + e0, (char*)Bs + c0 * 1024);
    gload_lds16(Bt + (size_t)r1 * K + k0 + e1, (char*)Bs + c1 * 1024);
    __syncthreads();
    bf16x8 af[4], bfv[4];
    for (int m = 0; m < 4; ++m)
      af[m] = *reinterpret_cast<const bf16x8*>(&As[(wr * 64 + m * 16 + lid) * 32 + lgrp * 8]);
    for (int n = 0; n < 4; ++n)
      bfv[n] = *reinterpret_cast<const bf16x8*>(&Bs[(wc * 64 + n * 16 + lid) * 32 + lgrp * 8]);
    for (int m = 0; m < 4; ++m)
      for (int n = 0; n < 4; ++n)
        acc[m][n] = __builtin_amdgcn_mfma_f32_16x16x32_bf16(af[m], bfv[n], acc[m][n], 0, 0, 0);
  }

  // C frag layout: row = (lane>>4)*4 + r, col = lane&15
  if (proj == 0) {  // Q plain [B,H,S,64]
    for (int m = 0; m < 4; ++m) {
      int rowb = m0 + wr * 64 + m * 16 + lgrp * 4;
      for (int n = 0; n < 4; ++n) {
        int col = n0 + wc * 64 + n * 16 + lid;
        int h = col >> 6, e = col & 63;
        for (int r = 0; r < 4; ++r) {
          int row = rowb + r;
          int b = row >> 11, s = row & 2047;
          Qh[(((size_t)b * 16 + h) * 2048 + s) * 64 + e] = (bf16)acc[m][n][r];
        }
      }
    }
  } else if (proj == 1) {  // K row-swizzled [B,H,S,64]
    for (int m = 0; m < 4; ++m) {
      int rowb = m0 + wr * 64 + m * 16 + lgrp * 4;
      for (int n = 0; n < 4; ++n) {
        int col = n0 + wc * 64 + n * 16 + lid;
        int h = col >> 6, e = col & 63;
        for (int r = 0; r < 4; ++r) {
          int row = rowb + r;
          int b = row >> 11, s = row & 2047;
          Kh[(((size_t)b * 16 + h) * 2048 + s) * 64 + (e ^ ((s & 7) << 3))] = (bf16)acc[m][n][r];
        }
      }
    }
  } else {  // V^T row-swizzled [B,H,64,S]; 4 consecutive s -> packed 8B store
    for (int m = 0; m < 4; ++m) {
      int rowb = m0 + wr * 64 + m * 16 + lgrp * 4;
      int b = rowb >> 11, s = rowb & 2047;
      for (int n = 0; n < 4; ++n) {
        int col = n0 + wc * 64 + n * 16 + lid;
        int h = col >> 6, e = col & 63;
        union { bf16 hv[4]; uint2 u; } tmp;
        for (int r = 0; r < 4; ++r) tmp.hv[r] = (bf16)acc[m][n][r];
        bf16* dst = Vt + (((size_t)b * 16 + h) * 64 + e) * 2048 + (s ^ ((e & 7) << 3));
        *reinterpret_cast<uint2*>(dst) = tmp.u;
      }
    }
  }
}

// ---------------- output-projection GEMM (f32 out) ----------------
__global__ __launch_bounds__(256) void k_gemm_out(const bf16* __restrict__ A,
                                                  const bf16* __restrict__ Bt,
                                                  float* __restrict__ C) {
  constexpr int K = 1024;
  __shared__ __align__(16) bf16 As[128 * 32];
  __shared__ __align__(16) bf16 Bs[128 * 32];
  const int tid = threadIdx.x;
  const int lane = tid & 63, w = tid >> 6;
  const int wr = w >> 1, wc = w & 1;
  const int lgrp = lane >> 4, lid = lane & 15;
  const int m0 = blockIdx.x * 128, n0 = blockIdx.y * 128;

  f32x4 acc[4][4] = {};
  const int c0 = w * 2, c1 = w * 2 + 1;
  const int bo0 = c0 * 1024 + lane * 16, bo1 = c1 * 1024 + lane * 16;
  const int r0 = bo0 >> 6, e0 = (bo0 & 63) >> 1;
  const int r1 = bo1 >> 6, e1 = (bo1 & 63) >> 1;

  for (int k0 = 0; k0 < K; k0 += 32) {
    __syncthreads();
    gload_lds16(A + (size_t)(m0 + r0) * K + k0 + e0, (char*)As + c0 * 1024);
    gload_lds16(A + (size_t)(m0 + r1) * K + k0 + e1, (char*)As + c1 * 1024);
    gload_lds16(Bt + (size_t)(n0 + r0) * K + k0 + e0, (char*)Bs + c0 * 1024);
    gload_lds16(Bt + (size_t)(n0 + r1) * K + k0 + e1, (char*)Bs + c1 * 1024);
    __syncthreads();
    bf16x8 af[4], bfv[4];
    for (int m = 0; m < 4; ++m)
      af[m] = *reinterpret_cast<const bf16x8*>(&As[(wr * 64 + m * 16 + lid) * 32 + lgrp * 8]);
    for (int n = 0; n < 4; ++n)
      bfv[n] = *reinterpret_cast<const bf16x8*>(&Bs[(wc * 64 + n * 16 + lid) * 32 + lgrp * 8]);
    for (int m = 0; m < 4; ++m)
      for (int n = 0; n < 4; ++n)
        acc[m][n] = __builtin_amdgcn_mfma_f32_16x16x32_bf16(af[m], bfv[n], acc[m][n], 0, 0, 0);
  }
  for (int m = 0; m < 4; ++m) {
    int rowb = m0 + wr * 64 + m * 16 + lgrp * 4;
    for (int n = 0; n < 4; ++n) {
      int col = n0 + wc * 64 + n * 16 + lid;
      for (int r = 0; r < 4; ++r)
        C[(size_t)(rowb + r) * 1024 + col] = acc[m][n][r];
    }
  }
}

// ---------------- flash attention ----------------
// 8 waves x 16 q-rows = 128 q/block; KV tile = 64 keys, LDS double-buffered.
// SWAPPED QK^T: sc = mfma(K_frag, Q_frag) -> row=key, col=q=lid. Each lane owns
// ONE q-row: mrow/lpart are scalars, defer-max check is 1 compare, P-writes are
// 8 packed ds_write_b32. Rare rescale / epilogue redistribute per-q values via
// a per-wave LDS float bounce.
__global__ __launch_bounds__(512) void k_flash(const bf16* __restrict__ Qh,
                                               const bf16* __restrict__ Ksw,
                                               const bf16* __restrict__ Vsw,
                                               const int* __restrict__ valid,
                                               bf16* __restrict__ Ob) {
  __shared__ __align__(16) char Ks[2][64 * 128];
  __shared__ __align__(16) char Vs[2][64 * 128];
  __shared__ __align__(16) char Plds[8][16 * 128];
  const int tid = threadIdx.x, lane = tid & 63, w = tid >> 6;
  const int lgrp = lane >> 4, lid = lane & 15;
  const int blk = blockIdx.x;
  const int qt = blk & 15, bh = blk >> 4;  // consecutive blocks share (b,h) -> L2 reuse
  const int b = bh >> 4, h = bh & 15;
  const int s0 = qt * 128 + w * 16;
  const bf16* Qp = Qh + ((size_t)bh * 2048 + s0) * 64;
  const bf16* Kp = Ksw + (size_t)bh * 2048 * 64;
  const bf16* Vp = Vsw + (size_t)bh * 64 * 2048;
  const int vl = valid[b];
  const int nt = (vl + 63) >> 6;
  const int full = vl >> 6;  // tiles with no masked key

  // staging: wave w stages rows [8w, 8w+8) of K and V (1 gload each)
  const int srow = 8 * w + (lane >> 3), col8 = (lane & 7) * 8;

  gload_lds16(Kp + (size_t)srow * 64 + col8, &Ks[0][(8 * w) * 128]);
  gload_lds16(Vp + (size_t)srow * 2048 + col8, &Vs[0][(8 * w) * 128]);

  bf16x8 aq0 = *reinterpret_cast<const bf16x8*>(Qp + lid * 64 + lgrp * 8);
  bf16x8 aq1 = *reinterpret_cast<const bf16x8*>(Qp + lid * 64 + 32 + lgrp * 8);

  f32x4 Of[4] = {};
  float mrow = -1e30f;  // running max for q = lid (lane-local!)
  float lpart = 0.f;    // partial l for q = lid over this lane's 16 k-slots
  char* Pw = &Plds[w][0];
  float* PwF = (float*)Pw;
  const int pswz = (lid & 7) << 4;

  int cur = 0;
  for (int t = 0; t < nt; ++t) {
    const int t0 = t * 64;
    __syncthreads();  // buf[cur] staged & visible (vmcnt drained at barrier)
    if (t + 1 < nt) {
      const int t1 = t0 + 64;
      gload_lds16(Kp + (size_t)(t1 + srow) * 64 + col8, &Ks[cur ^ 1][(8 * w) * 128]);
      gload_lds16(Vp + (size_t)srow * 2048 + t1 + col8, &Vs[cur ^ 1][(8 * w) * 128]);
    }
    // swapped scores: sc[ct][r] = S[key = t0+ct*16+lgrp*4+r][q = lid]
    f32x4 sc[4] = {};
#pragma unroll
    for (int ct = 0; ct < 4; ++ct) {
      const int row = ct * 16 + lid;
      const char* kb = &Ks[cur][row * 128];
      const int msk = (row & 7) << 4;
      bf16x8 bk0 = *reinterpret_cast<const bf16x8*>(kb + ((lgrp * 16) ^ msk));
      bf16x8 bk1 = *reinterpret_cast<const bf16x8*>(kb + ((64 + lgrp * 16) ^ msk));
      sc[ct] = __builtin_amdgcn_mfma_f32_16x16x32_bf16(bk0, aq0, sc[ct], 0, 0, 0);
      sc[ct] = __builtin_amdgcn_mfma_f32_16x16x32_bf16(bk1, aq1, sc[ct], 0, 0, 0);
    }
    if (t >= full) {  // only the single partial tile pays masking cost
#pragma unroll
      for (int ct = 0; ct < 4; ++ct)
#pragma unroll
        for (int r = 0; r < 4; ++r)
          sc[ct][r] = (t0 + ct * 16 + lgrp * 4 + r) >= vl ? -1e30f : sc[ct][r];
    }
    // lane-local max over this lane's 16 keys (all same q)
    float vm = fmaxf(fmaxf(fmaxf(sc[0][0], sc[0][1]), fmaxf(sc[0][2], sc[0][3])),
                     fmaxf(fmaxf(sc[1][0], sc[1][1]), fmaxf(sc[1][2], sc[1][3])));
    vm = fmaxf(vm, fmaxf(fmaxf(fmaxf(sc[2][0], sc[2][1]), fmaxf(sc[2][2], sc[2][3])),
                         fmaxf(fmaxf(sc[3][0], sc[3][1]), fmaxf(sc[3][2], sc[3][3]))));
    if (__any(vm > mrow + 8.f)) {  // rare after warm-up
      // full row max: combine the 4 lgrp-lanes holding q=lid
      vm = fmaxf(vm, __shfl_xor(vm, 16));
      vm = fmaxf(vm, __shfl_xor(vm, 32));
      float mnew = fmaxf(mrow, vm);
      float scl = fexp2(mrow - mnew);
      mrow = mnew;
      lpart *= scl;
      // redistribute scl (indexed by q=lid) to Of rows (q=lgrp*4+r)
      if (lgrp == 0) PwF[lid] = scl;
      asm volatile("s_waitcnt lgkmcnt(0)" ::: "memory");
      f32x4 sq = *reinterpret_cast<const f32x4*>(PwF + lgrp * 4);
#pragma unroll
      for (int f = 0; f < 4; ++f)
#pragma unroll
        for (int r = 0; r < 4; ++r)
          Of[f][r] *= sq[r];
    }
#pragma unroll
    for (int ct = 0; ct < 4; ++ct)
#pragma unroll
      for (int r = 0; r < 4; ++r)
        sc[ct][r] = fexp2(sc[ct][r] - mrow);  // bounded by 2^8
    // P[q=lid][k]: pack reg pairs -> 8 x ds_write_b32 (swizzled row lid)
#pragma unroll
    for (int ct = 0; ct < 4; ++ct) {
      union { bf16 hv[2]; unsigned int u; } p0, p1;
      p0.hv[0] = (bf16)sc[ct][0]; p0.hv[1] = (bf16)sc[ct][1];
      p1.hv[0] = (bf16)sc[ct][2]; p1.hv[1] = (bf16)sc[ct][3];
      char* base = Pw + lid * 128 + (((ct * 32 + lgrp * 8)) ^ pswz);
      *reinterpret_cast<unsigned int*>(base) = p0.u;
      *reinterpret_cast<unsigned int*>(base + 4) = p1.u;
    }
    asm volatile("s_waitcnt lgkmcnt(0)" ::: "memory");
    bf16x8 pa0 = *reinterpret_cast<const bf16x8*>(Pw + lid * 128 + ((lgrp * 16) ^ pswz));
    bf16x8 pa1 = *reinterpret_cast<const bf16x8*>(Pw + lid * 128 + ((64 + lgrp * 16) ^ pswz));
#pragma unroll
    for (int f = 0; f < 4; ++f) {
      const int row = f * 16 + lid;
      const char* vb = &Vs[cur][row * 128];
      const int msk = (row & 7) << 4;
      bf16x8 bv0 = *reinterpret_cast<const bf16x8*>(vb + ((lgrp * 16) ^ msk));
      bf16x8 bv1 = *reinterpret_cast<const bf16x8*>(vb + ((64 + lgrp * 16) ^ msk));
      Of[f] = __builtin_amdgcn_mfma_f32_16x16x32_bf16(pa0, bv0, Of[f], 0, 0, 0);
      Of[f] = __builtin_amdgcn_mfma_f32_16x16x32_bf16(pa1, bv1, Of[f], 0, 0, 0);
    }
    // lane-local partial l (reduced across lgrp-lanes in the epilogue)
    lpart += ((sc[0][0] + sc[0][1]) + (sc[0][2] + sc[0][3])) +
             ((sc[1][0] + sc[1][1]) + (sc[1][2] + sc[1][3])) +
             ((sc[2][0] + sc[2][1]) + (sc[2][2] + sc[2][3])) +
             ((sc[3][0] + sc[3][1]) + (sc[3][2] + sc[3][3]));
    cur ^= 1;
  }
  // epilogue: full l per q, redistribute 1/l to Of rows, store
  float l = lpart;
  l += __shfl_xor(l, 16);
  l += __shfl_xor(l, 32);
  float inv = 1.f / l;
  if (lgrp == 0) PwF[lid] = inv;
  asm volatile("s_waitcnt lgkmcnt(0)" ::: "memory");
  f32x4 invq = *reinterpret_cast<const f32x4*>(PwF + lgrp * 4);
  bf16* Op = Ob + ((size_t)b * 2048 + s0) * 1024 + h * 64;
#pragma unroll
  for (int r = 0; r < 4; ++r)
#pragma unroll
    for (int f = 0; f < 4; ++f)
      Op[(size_t)(lgrp * 4 + r) * 1024 + f * 16 + lid] = (bf16)(Of[f][r] * invq[r]);
}

// ---------------- launch ----------------
extern "C" void kernel_launch(void* const* d_in, const int* in_sizes, int n_in,
                              void* d_out, int out_size, void* d_ws, size_t ws_size,
                              hipStream_t stream) {
  const float* q = (const float*)d_in[0];
  const float* k = (const float*)d_in[1];
  const float* v = (const float*)d_in[2];
  const int* vl = (const int*)d_in[3];
  const float* Wq = (const float*)d_in[4];
  const float* Wk = (const float*)d_in[5];
  const float* Wv = (const float*)d_in[6];
  const float* Wo = (const float*)d_in[7];

  char* ws = (char*)d_ws;
  const size_t SZW = (size_t)1024 * 1024 * 2;  // 2MB per weight matrix
  const size_t SZT = (size_t)8192 * 1024 * 2;  // 16MB per bf16 activation tensor
  bf16* WqkvT = (bf16*)(ws);                   // 6MB [3072][1024]
  bf16* WoT = (bf16*)(ws + 3 * SZW);
  bf16* Qh  = (bf16*)(ws + 4 * SZW);
  bf16* Kh  = (bf16*)(ws + 4 * SZW + SZT);
  bf16* Vt  = (bf16*)(ws + 4 * SZW + 2 * SZT);
  bf16* qb  = (bf16*)(ws + 4 * SZW + 3 * SZT);
  bf16* kb  = (bf16*)(ws + 4 * SZW + 4 * SZT);
  bf16* vb  = (bf16*)(ws + 4 * SZW + 5 * SZT);
  bf16* attnb = qb;  // qb dead after projections

  k_cvt_act<<<12288, 256, 0, stream>>>(q, k, v, qb, kb, vb);
  k_cvt_w<<<16384, 256, 0, stream>>>(Wq, Wk, Wv, Wo, WqkvT, WoT);
  dim3 gq(64, 24);
  k_gemm_qkv<<<gq, 256, 0, stream>>>(qb, kb, vb, WqkvT, Qh, Kh, Vt);
  k_flash<<<1024, 512, 0, stream>>>(Qh, Kh, Vt, vl, attnb);
  dim3 go(64, 8);
  k_gemm_out<<<go, 256, 0, stream>>>(attnb, WoT, (float*)d_out);
}